// Round 9
// baseline (249.429 us; speedup 1.0000x reference)
//
#include <hip/hip_runtime.h>

typedef __attribute__((ext_vector_type(8))) short short8;
typedef __attribute__((ext_vector_type(4))) float f32x4;
typedef __attribute__((ext_vector_type(4))) unsigned int u32x4;

#define NTOK 4096
#define DIM  256
#define P_STRIDE 72          // P row stride elems (144 B)
#define XBF_ELEMS (4u * NTOK * DIM)   // bf16 row-major x copy
#define KT_TILE 16384        // elems per Kt tile image (32 KB): [8 kb][256 d][8 tok]

__device__ __forceinline__ unsigned pack2bf(float a, float b) {
  unsigned ua = __builtin_bit_cast(unsigned, a) + 0x8000u;
  unsigned ub = __builtin_bit_cast(unsigned, b) + 0x8000u;
  return __builtin_amdgcn_perm(ub, ua, 0x07060302u); // low=bf16(a), high=bf16(b)
}

// ---- prologue: Xbf (plain bf16 rows) + Kt tile images --------------------
__global__ __launch_bounds__(256, 4)
void prep_kernel(const float* __restrict__ X, unsigned short* __restrict__ Ws) {
  unsigned short* Xbf = Ws;
  unsigned short* Kti = Ws + XBF_ELEMS;
  const int b    = blockIdx.x & 3;
  const int sub  = blockIdx.x >> 2;   // 0..511
  const int t    = sub >> 3;
  const int part = sub & 7;           // eighth of the tile (8 tokens)
  const int tid  = threadIdx.x;
  const float* src = X + ((size_t)b * NTOK + t * 64) * DIM;
  // Xbf: 8 tokens x 256 d, plain row-major
  {
    int r = part * 8 + (tid >> 5);    // token within tile
    int c = tid & 31;                 // 8-elem chunk
    const float* s = src + r * DIM + c * 8;
    f32x4 f0 = *(const f32x4*)s;
    f32x4 f1 = *(const f32x4*)(s + 4);
    union { unsigned u[4]; u32x4 v; } p;
    p.u[0] = pack2bf(f0[0], f0[1]);
    p.u[1] = pack2bf(f0[2], f0[3]);
    p.u[2] = pack2bf(f1[0], f1[1]);
    p.u[3] = pack2bf(f1[2], f1[3]);
    *(u32x4*)(Xbf + ((size_t)b * NTOK + t * 64 + r) * DIM + c * 8) = p.v;
  }
  // Kt: kb-block = part; thread = d (coalesced dword reads)
  {
    const int d = tid;
    float f[8];
    #pragma unroll
    for (int i = 0; i < 8; ++i) f[i] = src[(part * 8 + i) * DIM + d];
    union { unsigned u[4]; u32x4 v; } p;
    p.u[0] = pack2bf(f[0], f[1]);
    p.u[1] = pack2bf(f[2], f[3]);
    p.u[2] = pack2bf(f[4], f[5]);
    p.u[3] = pack2bf(f[6], f[7]);
    *(u32x4*)(Kti + ((size_t)(b * 64 + t)) * KT_TILE + part * 2048 + d * 8) = p.v;
  }
}

// PV: O[s][dt] += P(strips of qh) x V(d-quarter role); P chunk kc at pos = kc ^ (2*(ln>>3))
__device__ __forceinline__ void pv_step(const unsigned short* __restrict__ pr,
                                        const unsigned short* __restrict__ kt,
                                        f32x4 (&o)[2][4],
                                        int qh, int role, int quad, int ln) {
  #pragma unroll
  for (int ks = 0; ks < 2; ++ks) {
    const int pos = (ks * 4 + quad) ^ ((ln >> 3) << 1);
    short8 ap[2], bv[4];
    #pragma unroll
    for (int s = 0; s < 2; ++s) {
      const int r = qh * 32 + s * 16 + ln;
      ap[s] = *(const short8*)(&pr[r * P_STRIDE + (pos << 3)]);
    }
    const unsigned short* kb = kt + (ks * 4 + quad) * 2048 + (role * 64 + ln) * 8;
    #pragma unroll
    for (int dt = 0; dt < 4; ++dt) bv[dt] = *(const short8*)(kb + dt * 128);
    #pragma unroll
    for (int s = 0; s < 2; ++s)
      #pragma unroll
      for (int dt = 0; dt < 4; ++dt)
        o[s][dt] = __builtin_amdgcn_mfma_f32_16x16x32_bf16(ap[s], bv[dt], o[s][dt], 0, 0, 0);
  }
}

// ---- flash-attention: K-stream from L2 via register prefetch; V+P in LDS -
__global__ __launch_bounds__(512, 1)
void fa_kernel(const unsigned short* __restrict__ Ws, float* __restrict__ Out) {
  __shared__ __align__(16) unsigned short ktb[2][KT_TILE];      // 64 KB
  __shared__ __align__(16) unsigned short pb[2][64 * P_STRIDE]; // 18 KB
  __shared__ float lbuf[64][4];                                 // 1 KB

  const unsigned short* Xbf = Ws;
  const unsigned short* Kti = Ws + XBF_ELEMS;

  const int tid  = threadIdx.x;
  const int b    = blockIdx.x & 3;
  const int qblk = blockIdx.x >> 2;
  const int wave = tid >> 6;
  const int lane = tid & 63;
  const int ln   = lane & 15;
  const int quad = lane >> 4;
  const int qh   = wave & 1;
  const int role = wave >> 1;

  const unsigned short* xb = Xbf + (size_t)b * NTOK * DIM;

  // Q fragments (plain layout): rows qblk*64 + qh*32 + s*16 + ln
  short8 aQ[2][8];
  #pragma unroll
  for (int s = 0; s < 2; ++s) {
    const unsigned short* qrow = xb + (size_t)(qblk * 64 + qh * 32 + s * 16 + ln) * DIM + quad * 8;
    #pragma unroll
    for (int ds = 0; ds < 8; ++ds)
      aQ[s][ds] = *(const short8*)(qrow + ds * 32);
  }

  f32x4 o[2][4];
  #pragma unroll
  for (int s = 0; s < 2; ++s)
    #pragma unroll
    for (int dt = 0; dt < 4; ++dt) o[s][dt] = (f32x4)(0.0f);
  float lrow[2][4] = {{0.f,0.f,0.f,0.f},{0.f,0.f,0.f,0.f}};

  const float c2 = 0.0901684400f;  // log2(e)/sqrt(256)

  // P write constants (R8 packed path)
  const int pwPos = ((role * 2 + (ln >> 3)) ^ ((quad >> 1) << 1)) << 3;
  const int pwCol = ln & 7;

  // Kt DMA: all 8 waves, 4 KB each (4 x 1KB bursts)
  const char* gKt = (const char*)(Kti + (size_t)b * 64 * KT_TILE) +
                    (size_t)wave * 4096 + (size_t)lane * 16;

  // K-stream register prefetch: this wave's 16 keys (role quarter), full rows
  const unsigned short* kstream = xb + (size_t)(role * 16 + ln) * DIM + quad * 8;
  short8 bk[8];
  #pragma unroll
  for (int ds = 0; ds < 8; ++ds)
    bk[ds] = *(const short8*)(kstream + ds * 32);   // tile 0

  for (int t = 0; t < 64; ++t) {
    __syncthreads();  // Kt(t-1) DMA drained; P dbuf swap safe
    const int buf = t & 1;

    // DMA Kt(t) -> ktb[buf] (consumed by PV at iter t+1)
    {
      const char* g = gKt + (size_t)t * 32768;
      unsigned short* l = &ktb[buf][wave * 2048];
      #pragma unroll
      for (int i = 0; i < 4; ++i)
        __builtin_amdgcn_global_load_lds(
            (const __attribute__((address_space(1))) unsigned*)(g + i * 1024),
            (__attribute__((address_space(3))) unsigned*)(l + i * 512),
            16, 0, 0);
    }

    // --- QK(t): keys role*16..+15 from bk regs, both strips ---
    f32x4 sf0 = (f32x4)(0.0f), sf1 = (f32x4)(0.0f);
    #pragma unroll
    for (int ds = 0; ds < 8; ++ds) {
      sf0 = __builtin_amdgcn_mfma_f32_16x16x32_bf16(aQ[0][ds], bk[ds], sf0, 0, 0, 0);
      sf1 = __builtin_amdgcn_mfma_f32_16x16x32_bf16(aQ[1][ds], bk[ds], sf1, 0, 0, 0);
    }

    // prefetch bk for tile t+1 (global/L2; no LDS, no barrier dependence)
    if (t < 63) {
      const unsigned short* kr = kstream + (size_t)(t + 1) * 64 * DIM;
      #pragma unroll
      for (int ds = 0; ds < 8; ++ds)
        bk[ds] = *(const short8*)(kr + ds * 32);
    }

    // --- softmax numerators; packed P store ---
    {
      unsigned short* pw = pb[buf];
      #pragma unroll
      for (int j = 0; j < 4; ++j) {
        float p0 = __builtin_amdgcn_exp2f(sf0[j] * c2);
        float p1 = __builtin_amdgcn_exp2f(sf1[j] * c2);
        lrow[0][j] += p0;
        lrow[1][j] += p1;
        unsigned q0 = __builtin_bit_cast(unsigned, p0);
        unsigned q1 = __builtin_bit_cast(unsigned, p1);
        unsigned n0 = (unsigned)__builtin_amdgcn_mov_dpp((int)q0, 0xB1, 0xF, 0xF, true);
        unsigned n1 = (unsigned)__builtin_amdgcn_mov_dpp((int)q1, 0xB1, 0xF, 0xF, true);
        if ((ln & 1) == 0) {
          const int r0 = qh * 32 + quad * 4 + j;
          unsigned d0 = pack2bf(__builtin_bit_cast(float, q0), __builtin_bit_cast(float, n0));
          unsigned d1 = pack2bf(__builtin_bit_cast(float, q1), __builtin_bit_cast(float, n1));
          *(unsigned*)(&pw[r0 * P_STRIDE + pwPos + pwCol]) = d0;
          *(unsigned*)(&pw[(r0 + 16) * P_STRIDE + pwPos + pwCol]) = d1;
        }
      }
    }

    // --- PV(t-1) ---
    if (t > 0)
      pv_step(pb[buf ^ 1], ktb[buf ^ 1], o, qh, role, quad, ln);
  }

  __syncthreads();  // P(63), Kt(63) resident
  pv_step(pb[1], ktb[1], o, qh, role, quad, ln);

  // --- merge l across roles, divide, store ---
  #pragma unroll
  for (int off = 1; off < 16; off <<= 1)
    #pragma unroll
    for (int s = 0; s < 2; ++s)
      #pragma unroll
      for (int j = 0; j < 4; ++j)
        lrow[s][j] += __shfl_xor(lrow[s][j], off, 64);
  if (ln == 0) {
    #pragma unroll
    for (int s = 0; s < 2; ++s)
      #pragma unroll
      for (int j = 0; j < 4; ++j)
        lbuf[qh * 32 + s * 16 + quad * 4 + j][role] = lrow[s][j];
  }
  __syncthreads();

  #pragma unroll
  for (int s = 0; s < 2; ++s) {
    float* outp = Out + (size_t)(b * NTOK + qblk * 64 + qh * 32 + s * 16) * DIM + role * 64;
    #pragma unroll
    for (int j = 0; j < 4; ++j) {
      const int row = s * 16 + quad * 4 + j;
      f32x4 lv = *(const f32x4*)lbuf[qh * 32 + row];
      const float rl = 1.0f / (lv[0] + lv[1] + lv[2] + lv[3]);
      #pragma unroll
      for (int dt = 0; dt < 4; ++dt)
        outp[(size_t)(quad * 4 + j) * DIM + dt * 16 + ln] = o[s][dt][j] * rl;
    }
  }
}

extern "C" void kernel_launch(void* const* d_in, const int* in_sizes, int n_in,
                              void* d_out, int out_size, void* d_ws, size_t ws_size,
                              hipStream_t stream) {
  const float* X = (const float*)d_in[0];       // x: fp32 [4,4096,256]
  float* Out = (float*)d_out;                   // fp32 [4,4096,256]
  unsigned short* Ws = (unsigned short*)d_ws;   // 8 MB Xbf + 8 MB Kt images
  (void)in_sizes; (void)n_in; (void)out_size; (void)ws_size;
  hipLaunchKernelGGL(prep_kernel, dim3(2048), dim3(256), 0, stream, X, Ws);
  hipLaunchKernelGGL(fa_kernel, dim3(256), dim3(512), 0, stream, Ws, Out);
}

// Round 10
// 176.581 us; speedup vs baseline: 1.4125x; 1.4125x over previous
//
#include <hip/hip_runtime.h>

typedef __attribute__((ext_vector_type(8))) short short8;
typedef __attribute__((ext_vector_type(4))) float f32x4;
typedef __attribute__((ext_vector_type(4))) unsigned int u32x4;
typedef __attribute__((ext_vector_type(2))) long long2_t;

#define NTOK 4096
#define DIM  256
#define P_STRIDE 72            // P row stride elems (144 B)
#define KS_ROW 272             // fp8 Ks row stride bytes (256 + 16 pad)
#define KS_TILE 17408          // 64 * 272 bytes (= 17 KB, 17 x 1KB bursts)
#define KT_TILE 16384          // ushorts per Kt tile (32 KB): [8 kb][256 d][8 tok]
#define KSF8_BYTES (4u * 64u * KS_TILE)   // 4.25 MB

__device__ __forceinline__ unsigned pack2bf(float a, float b) {
  unsigned ua = __builtin_bit_cast(unsigned, a) + 0x8000u;
  unsigned ub = __builtin_bit_cast(unsigned, b) + 0x8000u;
  return __builtin_amdgcn_perm(ub, ua, 0x07060302u);
}

// ---- prologue: fp8 Ks images (MFMA-permuted rows) + bf16 Kt images -------
// Ks row layout: byte pos = ds2*64 + quad*16 + half*8 + j  <->  d = (2*ds2+half)*32 + quad*8 + j
__global__ __launch_bounds__(256, 4)
void prep_kernel(const float* __restrict__ X, unsigned char* __restrict__ Ws) {
  unsigned char*  Ksf8 = Ws;
  unsigned short* KtImg = (unsigned short*)(Ws + KSF8_BYTES);
  const int b    = blockIdx.x & 3;
  const int sub  = blockIdx.x >> 2;   // 0..511
  const int t    = sub >> 3;
  const int part = sub & 7;           // eighth of tile (8 tokens)
  const int tid  = threadIdx.x;
  const float* src = X + ((size_t)b * NTOK + t * 64) * DIM;
  // Ks-fp8: rows part*8..+7, 64 data dwords per row (68 incl pad, pad skipped)
  unsigned char* dstK = Ksf8 + (size_t)(b * 64 + t) * KS_TILE;
  #pragma unroll
  for (int i = 0; i < 3; ++i) {
    int idx = tid + i * 256;          // 0..543
    if (idx < 544) {
      int rl = idx / 68, w = idx % 68;
      if (w < 64) {
        int r = part * 8 + rl;
        int ds2 = w >> 4, rem = (w & 15) << 2;   // rem = 4w % 64
        int quad = rem >> 4, rem2 = rem & 15;
        int half = rem2 >> 3, j0 = rem2 & 7;
        int d0 = (2 * ds2 + half) * 32 + quad * 8 + j0;
        const float* s = src + r * DIM + d0;
        int u = 0;
        u = __builtin_amdgcn_cvt_pk_fp8_f32(s[0], s[1], u, false);
        u = __builtin_amdgcn_cvt_pk_fp8_f32(s[2], s[3], u, true);
        *(int*)(dstK + r * KS_ROW + w * 4) = u;
      }
    }
  }
  // Kt bf16: kb-block = part; thread = d (coalesced dword reads)
  {
    const int d = tid;
    float f[8];
    #pragma unroll
    for (int i = 0; i < 8; ++i) f[i] = src[(part * 8 + i) * DIM + d];
    union { unsigned u[4]; u32x4 v; } p;
    p.u[0] = pack2bf(f[0], f[1]);
    p.u[1] = pack2bf(f[2], f[3]);
    p.u[2] = pack2bf(f[4], f[5]);
    p.u[3] = pack2bf(f[6], f[7]);
    *(u32x4*)(KtImg + ((size_t)(b * 64 + t)) * KT_TILE + part * 2048 + d * 8) = p.v;
  }
}

// PV: O[s][dt] += P(all 4 strips, k-half ks) x V(d-quarter dq)
__device__ __forceinline__ void pv_step(const unsigned short* __restrict__ pr,
                                        const unsigned short* __restrict__ kt,
                                        f32x4 (&o)[4][4],
                                        int ks, int dq, int quad, int ln) {
  const int pos = (ks * 4 + quad) ^ ((ln >> 3) << 1);
  short8 ap[4], bv[4];
  #pragma unroll
  for (int s = 0; s < 4; ++s)
    ap[s] = *(const short8*)(&pr[(s * 16 + ln) * P_STRIDE + (pos << 3)]);
  const unsigned short* kb = kt + (ks * 4 + quad) * 2048 + (dq * 64 + ln) * 8;
  #pragma unroll
  for (int dt = 0; dt < 4; ++dt) bv[dt] = *(const short8*)(kb + dt * 128);
  #pragma unroll
  for (int s = 0; s < 4; ++s)
    #pragma unroll
    for (int dt = 0; dt < 4; ++dt)
      o[s][dt] = __builtin_amdgcn_mfma_f32_16x16x32_bf16(ap[s], bv[dt], o[s][dt], 0, 0, 0);
}

// ---- flash-attention: fp8 QK, bf16 PV, 1 barrier/iter, all-DMA staging ---
__global__ __launch_bounds__(512, 1)
void fa_kernel(const unsigned char* __restrict__ Ws, float* __restrict__ Out) {
  __shared__ __align__(16) unsigned char  ksb[2][KS_TILE];       // 34 KB fp8
  __shared__ __align__(16) unsigned short ktb[2][KT_TILE];       // 64 KB bf16
  __shared__ __align__(16) unsigned short pb[2][64 * P_STRIDE];  // 18 KB
  __shared__ float lbuf[64][4];                                  // 1 KB

  const unsigned char*  Ksf8 = Ws;
  const unsigned short* KtImg = (const unsigned short*)(Ws + KSF8_BYTES);

  const int tid  = threadIdx.x;
  const int b    = blockIdx.x & 3;
  const int qblk = blockIdx.x >> 2;
  const int wave = tid >> 6;
  const int lane = tid & 63;
  const int ln   = lane & 15;
  const int quad = lane >> 4;
  const int qh   = wave & 1;    // QK: Q-half          PV: k-half (ks)
  const int kq   = wave >> 1;   // QK: key-quarter     PV: d-quarter (dq)

  const unsigned char*  ksImgB = Ksf8 + (size_t)b * 64 * KS_TILE;
  const unsigned short* ktImgB = KtImg + (size_t)b * 64 * KT_TILE;

  // Q fragments (fp8, from the permuted Ks image of tile qblk)
  long aQ[2][8];
  #pragma unroll
  for (int s = 0; s < 2; ++s) {
    const unsigned char* qrow =
        ksImgB + (size_t)qblk * KS_TILE + (qh * 32 + s * 16 + ln) * KS_ROW;
    #pragma unroll
    for (int ds2 = 0; ds2 < 4; ++ds2) {
      long2_t v = *(const long2_t*)(qrow + ds2 * 64 + quad * 16);
      aQ[s][2 * ds2]     = v.x;
      aQ[s][2 * ds2 + 1] = v.y;
    }
  }

  f32x4 o[4][4];
  #pragma unroll
  for (int s = 0; s < 4; ++s)
    #pragma unroll
    for (int dt = 0; dt < 4; ++dt) o[s][dt] = (f32x4)(0.0f);
  float lrow[2][4] = {{0.f,0.f,0.f,0.f},{0.f,0.f,0.f,0.f}};

  const float c2 = 0.0901684400f;  // log2(e)/sqrt(256)
  const int pwPos = ((kq * 2 + (ln >> 3)) ^ ((quad >> 1) << 1)) << 3;
  const int pwCol = ln & 7;

  // prologue: Ks(0) -> ksb[0] (17 bursts over 8 waves)
  #pragma unroll
  for (int i = 0; i < 3; ++i) {
    int idx = wave + i * 8;
    if (idx < 17)
      __builtin_amdgcn_global_load_lds(
          (const __attribute__((address_space(1))) unsigned*)(ksImgB + idx * 1024 + lane * 16),
          (__attribute__((address_space(3))) unsigned*)(&ksb[0][idx * 1024 + lane * 16]),
          16, 0, 0);
  }

  for (int t = 0; t < 64; ++t) {
    __syncthreads();  // drains last iter's DMA; Ks(t)/Kt(t-1)/P(t-1) ready
    const int buf = t & 1;

    // DMA: Ks(t+1) -> ksb[buf^1] (17 bursts), Kt(t) -> ktb[buf] (32 bursts)
    #pragma unroll
    for (int i = 0; i < 7; ++i) {
      int idx = wave + i * 8;
      if (idx < 17) {
        if (t < 63)
          __builtin_amdgcn_global_load_lds(
              (const __attribute__((address_space(1))) unsigned*)
                  (ksImgB + (size_t)(t + 1) * KS_TILE + idx * 1024 + lane * 16),
              (__attribute__((address_space(3))) unsigned*)(&ksb[buf ^ 1][idx * 1024 + lane * 16]),
              16, 0, 0);
      } else if (idx < 49) {
        int k = idx - 17;
        __builtin_amdgcn_global_load_lds(
            (const __attribute__((address_space(1))) unsigned*)
                ((const unsigned char*)(ktImgB + (size_t)t * KT_TILE) + k * 1024 + lane * 16),
            (__attribute__((address_space(3))) unsigned*)(&ktb[buf][k * 512 + lane * 8]),
            16, 0, 0);
      }
    }

    // --- QK(t): fp8, keys kq*16..+15, both strips ---
    f32x4 sf0 = (f32x4)(0.0f), sf1 = (f32x4)(0.0f);
    {
      const unsigned char* krow = &ksb[buf][(kq * 16 + ln) * KS_ROW];
      #pragma unroll
      for (int ds2 = 0; ds2 < 4; ++ds2) {
        long2_t bk = *(const long2_t*)(krow + ds2 * 64 + quad * 16);
        sf0 = __builtin_amdgcn_mfma_f32_16x16x32_fp8_fp8(aQ[0][2*ds2],   bk.x, sf0, 0, 0, 0);
        sf0 = __builtin_amdgcn_mfma_f32_16x16x32_fp8_fp8(aQ[0][2*ds2+1], bk.y, sf0, 0, 0, 0);
        sf1 = __builtin_amdgcn_mfma_f32_16x16x32_fp8_fp8(aQ[1][2*ds2],   bk.x, sf1, 0, 0, 0);
        sf1 = __builtin_amdgcn_mfma_f32_16x16x32_fp8_fp8(aQ[1][2*ds2+1], bk.y, sf1, 0, 0, 0);
      }
    }
    // --- softmax numerators; packed P store (R8 path) ---
    {
      unsigned short* pw = pb[buf];
      #pragma unroll
      for (int j = 0; j < 4; ++j) {
        float p0 = __builtin_amdgcn_exp2f(sf0[j] * c2);
        float p1 = __builtin_amdgcn_exp2f(sf1[j] * c2);
        lrow[0][j] += p0;
        lrow[1][j] += p1;
        unsigned q0 = __builtin_bit_cast(unsigned, p0);
        unsigned q1 = __builtin_bit_cast(unsigned, p1);
        unsigned n0 = (unsigned)__builtin_amdgcn_mov_dpp((int)q0, 0xB1, 0xF, 0xF, true);
        unsigned n1 = (unsigned)__builtin_amdgcn_mov_dpp((int)q1, 0xB1, 0xF, 0xF, true);
        if ((ln & 1) == 0) {
          const int r0 = qh * 32 + quad * 4 + j;
          unsigned d0 = pack2bf(__builtin_bit_cast(float, q0), __builtin_bit_cast(float, n0));
          unsigned d1 = pack2bf(__builtin_bit_cast(float, q1), __builtin_bit_cast(float, n1));
          *(unsigned*)(&pw[r0 * P_STRIDE + pwPos + pwCol]) = d0;
          *(unsigned*)(&pw[(r0 + 16) * P_STRIDE + pwPos + pwCol]) = d1;
        }
      }
    }

    // --- PV(t-1): all strips, d-quarter kq, k-half qh ---
    if (t > 0)
      pv_step(pb[buf ^ 1], ktb[buf ^ 1], o, qh, kq, quad, ln);
  }

  __syncthreads();  // P(63), Kt(63) resident
  pv_step(pb[1], ktb[1], o, qh, kq, quad, ln);

  // --- merge l across key-quarters ---
  #pragma unroll
  for (int off = 1; off < 16; off <<= 1)
    #pragma unroll
    for (int s = 0; s < 2; ++s)
      #pragma unroll
      for (int j = 0; j < 4; ++j)
        lrow[s][j] += __shfl_xor(lrow[s][j], off, 64);
  if (ln == 0) {
    #pragma unroll
    for (int s = 0; s < 2; ++s)
      #pragma unroll
      for (int j = 0; j < 4; ++j)
        lbuf[qh * 32 + s * 16 + quad * 4 + j][kq] = lrow[s][j];
  }
  __syncthreads();

  // --- merge o k-halves through dead ktb, divide by l, store ---
  float* om = (float*)&ktb[0][0];  // 16384 floats: [dq][s*4+dt][lane][4]
  if (qh == 1) {
    #pragma unroll
    for (int s = 0; s < 4; ++s)
      #pragma unroll
      for (int dt = 0; dt < 4; ++dt)
        *(f32x4*)(om + kq * 4096 + (s * 4 + dt) * 256 + lane * 4) = o[s][dt];
  }
  __syncthreads();
  if (qh == 0) {
    float* outp = Out + (size_t)(b * NTOK + qblk * 64) * DIM + kq * 64;
    #pragma unroll
    for (int s = 0; s < 4; ++s) {
      #pragma unroll
      for (int dt = 0; dt < 4; ++dt) {
        f32x4 oo = o[s][dt] + *(const f32x4*)(om + kq * 4096 + (s * 4 + dt) * 256 + lane * 4);
        #pragma unroll
        for (int j = 0; j < 4; ++j) {
          const int row = s * 16 + quad * 4 + j;
          f32x4 lv = *(const f32x4*)lbuf[row];
          outp[(size_t)row * DIM + dt * 16 + ln] = oo[j] / (lv[0] + lv[1] + lv[2] + lv[3]);
        }
      }
    }
  }
}

extern "C" void kernel_launch(void* const* d_in, const int* in_sizes, int n_in,
                              void* d_out, int out_size, void* d_ws, size_t ws_size,
                              hipStream_t stream) {
  const float* X = (const float*)d_in[0];       // x: fp32 [4,4096,256]
  float* Out = (float*)d_out;                   // fp32 [4,4096,256]
  unsigned char* Ws = (unsigned char*)d_ws;     // 4.25 MB fp8 Ks + 8 MB bf16 Kt
  (void)in_sizes; (void)n_in; (void)out_size; (void)ws_size;
  hipLaunchKernelGGL(prep_kernel, dim3(2048), dim3(256), 0, stream, X, Ws);
  hipLaunchKernelGGL(fa_kernel, dim3(256), dim3(512), 0, stream, Ws, Out);
}